// Round 1
// baseline (1270.785 us; speedup 1.0000x reference)
//
#include <hip/hip_runtime.h>
#include <hip/hip_bf16.h>
#include <math.h>

#define N_TOK 4096
#define CA 768
#define CS 384
#define CZ 128
#define NHEAD 16
#define DH 48
#define NQW 32
#define NKW 128
#define NBLK 128

__device__ __forceinline__ float sigmoidf_(float x){ return 1.0f/(1.0f+__expf(-x)); }

// ---------------- LayerNorm kernels (wave per row) ----------------
__global__ __launch_bounds__(64) void ln_s_kernel(const float* __restrict__ s,
                                                  const float* __restrict__ gamma,
                                                  float* __restrict__ out){
  int row = blockIdx.x, lane = threadIdx.x;
  const float* x = s + (size_t)row*CS;
  float v[6]; float sum=0.f, sq=0.f;
  #pragma unroll
  for (int i=0;i<6;i++){ v[i]=x[lane+64*i]; sum+=v[i]; sq+=v[i]*v[i]; }
  #pragma unroll
  for (int off=32; off; off>>=1){ sum+=__shfl_xor(sum,off); sq+=__shfl_xor(sq,off); }
  float m = sum*(1.f/CS);
  float var = sq*(1.f/CS)-m*m;
  float rs = rsqrtf(var+1e-5f);
  float* o = out + (size_t)row*CS;
  #pragma unroll
  for (int i=0;i<6;i++) o[lane+64*i] = (v[i]-m)*rs*gamma[lane+64*i];
}

__global__ __launch_bounds__(64) void ln_a_kernel(const float* __restrict__ a,
                                                  float* __restrict__ out){
  int row = blockIdx.x, lane = threadIdx.x;
  const float* x = a + (size_t)row*CA;
  float v[12]; float sum=0.f, sq=0.f;
  #pragma unroll
  for (int i=0;i<12;i++){ v[i]=x[lane+64*i]; sum+=v[i]; sq+=v[i]*v[i]; }
  #pragma unroll
  for (int off=32; off; off>>=1){ sum+=__shfl_xor(sum,off); sq+=__shfl_xor(sq,off); }
  float m = sum*(1.f/CA);
  float var = sq*(1.f/CA)-m*m;
  float rs = rsqrtf(var+1e-5f);
  float* o = out + (size_t)row*CA;
  #pragma unroll
  for (int i=0;i<12;i++) o[lane+64*i] = (v[i]-m)*rs;
}

// ---------------- z bias kernel: bias[(w,q,k), h] = LN(z_row)*gamma @ wz ----------------
__global__ __launch_bounds__(256) void zbias_kernel(const float* __restrict__ z,
                                                    const float* __restrict__ gamma,
                                                    const float* __restrict__ wz,
                                                    float* __restrict__ biasb){
  __shared__ float wzs[CZ*NHEAD];     // 8 KB
  __shared__ float xns[4][CZ];
  for (int i = threadIdx.x; i < CZ*NHEAD; i += 256) wzs[i] = wz[i];
  int wave = threadIdx.x >> 6, lane = threadIdx.x & 63;
  size_t row = (size_t)blockIdx.x*4 + wave;
  const float* zr = z + row*CZ;
  float x0 = zr[lane], x1 = zr[lane+64];
  float s = x0 + x1, s2 = x0*x0 + x1*x1;
  #pragma unroll
  for (int off=32; off; off>>=1){ s += __shfl_xor(s,off); s2 += __shfl_xor(s2,off); }
  float m = s*(1.f/CZ);
  float var = s2*(1.f/CZ) - m*m;
  float rs = rsqrtf(var + 1e-5f);
  xns[wave][lane]    = (x0-m)*rs*gamma[lane];
  xns[wave][lane+64] = (x1-m)*rs*gamma[lane+64];
  __syncthreads();
  int h = lane & 15, part = lane >> 4;
  const float* xr = xns[wave];
  float acc = 0.f;
  #pragma unroll
  for (int i=0;i<32;i++){ int kk = part*32 + i; acc += xr[kk]*wzs[kk*NHEAD+h]; }
  acc += __shfl_xor(acc, 16);
  acc += __shfl_xor(acc, 32);
  if (lane < 16) biasb[row*NHEAD + h] = acc;
}

// ---------------- fused tiled GEMM (fp32, 64x64x16 tiles, 4x4 per thread) ----------------
// mode 0: out = A1@W1 + b1
// mode 1: out = sigmoid(A1@W1 + b1)
// mode 2: out = sigmoid(A1@W1 + b1) * aux + A2@W2          (adaln)
// mode 3: out = sigmoid(A2@W2 + b2) * (A1@W1 + b1)         (final)
__global__ __launch_bounds__(256) void gemm_fused(
  const float* __restrict__ A1, const float* __restrict__ W1, const float* __restrict__ b1, int K1,
  const float* __restrict__ A2, const float* __restrict__ W2, const float* __restrict__ b2, int K2,
  const float* __restrict__ aux, float* __restrict__ out, int M, int N, int mode)
{
  __shared__ float As[16][64];
  __shared__ float Bs[16][64];
  int tid = threadIdx.x;
  int m0 = blockIdx.y*64, n0 = blockIdx.x*64;
  int tx = tid & 15, ty = tid >> 4;
  int la_m = tid >> 2, la_k = (tid & 3)*4;
  int lw_k = tid >> 4, lw_n = (tid & 15)*4;
  float acc1[4][4] = {};
  float acc2[4][4] = {};

  for (int k0=0;k0<K1;k0+=16){
    float4 av = *(const float4*)(A1 + (size_t)(m0+la_m)*K1 + k0 + la_k);
    float4 wv = *(const float4*)(W1 + (size_t)(k0+lw_k)*N + n0 + lw_n);
    __syncthreads();
    As[la_k+0][la_m]=av.x; As[la_k+1][la_m]=av.y; As[la_k+2][la_m]=av.z; As[la_k+3][la_m]=av.w;
    *(float4*)&Bs[lw_k][lw_n] = wv;
    __syncthreads();
    #pragma unroll
    for (int kk=0;kk<16;kk++){
      float ar[4], br[4];
      #pragma unroll
      for (int i=0;i<4;i++) ar[i]=As[kk][ty*4+i];
      #pragma unroll
      for (int j=0;j<4;j++) br[j]=Bs[kk][tx*4+j];
      #pragma unroll
      for (int i=0;i<4;i++)
        #pragma unroll
        for (int j=0;j<4;j++) acc1[i][j] += ar[i]*br[j];
    }
  }
  if (A2 != nullptr){
    for (int k0=0;k0<K2;k0+=16){
      float4 av = *(const float4*)(A2 + (size_t)(m0+la_m)*K2 + k0 + la_k);
      float4 wv = *(const float4*)(W2 + (size_t)(k0+lw_k)*N + n0 + lw_n);
      __syncthreads();
      As[la_k+0][la_m]=av.x; As[la_k+1][la_m]=av.y; As[la_k+2][la_m]=av.z; As[la_k+3][la_m]=av.w;
      *(float4*)&Bs[lw_k][lw_n] = wv;
      __syncthreads();
      #pragma unroll
      for (int kk=0;kk<16;kk++){
        float ar[4], br[4];
        #pragma unroll
        for (int i=0;i<4;i++) ar[i]=As[kk][ty*4+i];
        #pragma unroll
        for (int j=0;j<4;j++) br[j]=Bs[kk][tx*4+j];
        #pragma unroll
        for (int i=0;i<4;i++)
          #pragma unroll
          for (int j=0;j<4;j++) acc2[i][j] += ar[i]*br[j];
      }
    }
  }
  #pragma unroll
  for (int i=0;i<4;i++){
    int row = m0 + ty*4 + i;
    #pragma unroll
    for (int j=0;j<4;j++){
      int col = n0 + tx*4 + j;
      float x1 = acc1[i][j] + (b1 ? b1[col] : 0.f);
      float val;
      if (mode == 0)      val = x1;
      else if (mode == 1) val = sigmoidf_(x1);
      else if (mode == 2) val = sigmoidf_(x1)*aux[(size_t)row*N+col] + acc2[i][j];
      else {
        float x2 = acc2[i][j] + (b2 ? b2[col] : 0.f);
        val = sigmoidf_(x2)*x1;
      }
      out[(size_t)row*N+col] = val;
    }
  }
}

// ---------------- local attention: one block per (w, h) ----------------
__global__ __launch_bounds__(256) void attn_kernel(
  const float* __restrict__ qb, const float* __restrict__ kb, const float* __restrict__ vb,
  const float* __restrict__ gb, const float* __restrict__ biasb, float* __restrict__ outg)
{
  const int w = blockIdx.x, h = blockIdx.y;
  __shared__ float qs[NQW][DH];        // 6 KB
  __shared__ float kvs[NKW][DH+1];     // 25 KB (pad 49: 8-lane k-groups conflict-free)
  __shared__ float sc[NQW][NKW];       // 16 KB
  int tid = threadIdx.x;
  int start = w*NQW - 48;

  for (int idx=tid; idx<NQW*DH; idx+=256){
    int r = idx/DH, d = idx - r*DH;
    qs[r][d] = qb[(size_t)(w*NQW+r)*CA + h*DH + d];
  }
  for (int idx=tid; idx<NKW*DH; idx+=256){
    int r = idx/DH, d = idx - r*DH;
    int kr = min(max(start+r,0),N_TOK-1);
    kvs[r][d] = kb[(size_t)kr*CA + h*DH + d];
  }
  __syncthreads();

  const float scale = 0.14433756729740643f;  // 1/sqrt(48)
  int r = tid >> 3, sub = tid & 7;
  #pragma unroll
  for (int j=0;j<16;j++){
    int k = sub + 8*j;
    float dot = 0.f;
    #pragma unroll
    for (int d=0; d<DH; d++) dot += qs[r][d]*kvs[k][d];
    int kg = start + k;
    float bv = biasb[((size_t)(w*NQW+r)*NKW + k)*NHEAD + h];
    sc[r][k] = (kg>=0 && kg<N_TOK) ? (dot*scale + bv) : -1e9f;
  }
  __syncthreads();

  // overwrite kvs with V while doing softmax
  for (int idx=tid; idx<NKW*DH; idx+=256){
    int rr = idx/DH, d = idx - rr*DH;
    int kr = min(max(start+rr,0),N_TOK-1);
    kvs[rr][d] = vb[(size_t)kr*CA + h*DH + d];
  }
  int wave = tid >> 6, lane = tid & 63;
  for (int rr=0; rr<8; rr++){
    int row = wave*8 + rr;
    float v0 = sc[row][lane], v1 = sc[row][lane+64];
    float mx = fmaxf(v0, v1);
    #pragma unroll
    for (int off=32; off; off>>=1) mx = fmaxf(mx, __shfl_xor(mx,off));
    float e0 = __expf(v0-mx), e1 = __expf(v1-mx);
    float sm = e0+e1;
    #pragma unroll
    for (int off=32; off; off>>=1) sm += __shfl_xor(sm,off);
    float inv = 1.f/sm;
    sc[row][lane] = e0*inv; sc[row][lane+64] = e1*inv;
  }
  __syncthreads();

  for (int idx=tid; idx<NQW*DH; idx+=256){
    int rr = idx/DH, d = idx - rr*DH;
    float o = 0.f;
    for (int k=0;k<NKW;k++) o += sc[rr][k]*kvs[k][d];
    size_t gi = (size_t)(w*NQW+rr)*CA + h*DH + d;
    outg[gi] = o * gb[gi];
  }
}

extern "C" void kernel_launch(void* const* d_in, const int* in_sizes, int n_in,
                              void* d_out, int out_size, void* d_ws, size_t ws_size,
                              hipStream_t stream)
{
  const float* a            = (const float*)d_in[0];
  const float* s            = (const float*)d_in[1];
  const float* z            = (const float*)d_in[2];
  const float* adaln_gamma  = (const float*)d_in[3];
  const float* adaln_ws     = (const float*)d_in[4];
  const float* adaln_bs     = (const float*)d_in[5];
  const float* adaln_wskip  = (const float*)d_in[6];
  const float* lnz_gamma    = (const float*)d_in[7];
  const float* wz           = (const float*)d_in[8];
  const float* wq           = (const float*)d_in[9];
  const float* bq           = (const float*)d_in[10];
  const float* wk           = (const float*)d_in[11];
  const float* wv           = (const float*)d_in[12];
  const float* wg           = (const float*)d_in[13];
  const float* bg           = (const float*)d_in[14];
  const float* wo           = (const float*)d_in[15];
  const float* bo           = (const float*)d_in[16];
  const float* w_last       = (const float*)d_in[17];
  const float* b_last       = (const float*)d_in[18];
  float* out = (float*)d_out;

  float* p = (float*)d_ws;
  float* s_ln  = p; p += (size_t)N_TOK*CS;
  float* a_n   = p; p += (size_t)N_TOK*CA;
  float* a_ln  = p; p += (size_t)N_TOK*CA;
  float* qb    = p; p += (size_t)N_TOK*CA;   // reused as gated attn output
  float* kbuf  = p; p += (size_t)N_TOK*CA;
  float* vbuf  = p; p += (size_t)N_TOK*CA;
  float* gbuf  = p; p += (size_t)N_TOK*CA;
  float* biasb = p; p += (size_t)NBLK*NQW*NKW*NHEAD;

  dim3 gemm_grid(CA/64, N_TOK/64);

  ln_s_kernel<<<dim3(N_TOK), dim3(64), 0, stream>>>(s, adaln_gamma, s_ln);
  ln_a_kernel<<<dim3(N_TOK), dim3(64), 0, stream>>>(a, a_n);

  // a_ln = sigmoid(s_ln@ws + bs)*LN(a) + s_ln@wskip
  gemm_fused<<<gemm_grid, 256, 0, stream>>>(s_ln, adaln_ws, adaln_bs, CS,
                                            s_ln, adaln_wskip, nullptr, CS,
                                            a_n, a_ln, N_TOK, CA, 2);

  // bias = LN(z)*gamma @ wz  (stored as [(w,q,k), h])
  zbias_kernel<<<dim3((NBLK*NQW*NKW)/4), 256, 0, stream>>>(z, lnz_gamma, wz, biasb);

  gemm_fused<<<gemm_grid, 256, 0, stream>>>(a_ln, wq, bq, CA,
                                            nullptr, nullptr, nullptr, 0,
                                            nullptr, qb, N_TOK, CA, 0);
  gemm_fused<<<gemm_grid, 256, 0, stream>>>(a_ln, wk, nullptr, CA,
                                            nullptr, nullptr, nullptr, 0,
                                            nullptr, kbuf, N_TOK, CA, 0);
  gemm_fused<<<gemm_grid, 256, 0, stream>>>(a_ln, wv, nullptr, CA,
                                            nullptr, nullptr, nullptr, 0,
                                            nullptr, vbuf, N_TOK, CA, 0);
  gemm_fused<<<gemm_grid, 256, 0, stream>>>(a_ln, wg, bg, CA,
                                            nullptr, nullptr, nullptr, 0,
                                            nullptr, gbuf, N_TOK, CA, 1);

  attn_kernel<<<dim3(NBLK, NHEAD), 256, 0, stream>>>(qb, kbuf, vbuf, gbuf, biasb, qb);

  // out = sigmoid(s@w_last + b_last) * (gated@wo + bo)
  gemm_fused<<<gemm_grid, 256, 0, stream>>>(qb, wo, bo, CA,
                                            s, w_last, b_last, CS,
                                            nullptr, out, N_TOK, CA, 3);
}

// Round 2
// 849.256 us; speedup vs baseline: 1.4964x; 1.4964x over previous
//
#include <hip/hip_runtime.h>
#include <hip/hip_bf16.h>
#include <math.h>

#define N_TOK 4096
#define CA 768
#define CS 384
#define CZ 128
#define NHEAD 16
#define DH 48
#define NQW 32
#define NKW 128
#define NBLK 128

typedef __attribute__((ext_vector_type(8))) short short8;
typedef __attribute__((ext_vector_type(4))) float float4v;

__device__ __forceinline__ float sigmoidf_(float x){ return 1.0f/(1.0f+__expf(-x)); }

__device__ __forceinline__ void split2(float x, __hip_bfloat16& h, __hip_bfloat16& l){
  h = __float2bfloat16(x);
  l = __float2bfloat16(x - __bfloat162float(h));
}

__device__ __forceinline__ void gload_lds16(const void* gsrc, void* ldst){
  __builtin_amdgcn_global_load_lds(
    (const __attribute__((address_space(1))) void*)gsrc,
    (__attribute__((address_space(3))) void*)ldst, 16, 0, 0);
}

// ---------------- LN(s)*gamma -> split bf16 ----------------
__global__ __launch_bounds__(64) void ln_s_kernel(const float* __restrict__ s,
                                                  const float* __restrict__ gamma,
                                                  __hip_bfloat16* __restrict__ oh,
                                                  __hip_bfloat16* __restrict__ ol){
  int row = blockIdx.x, lane = threadIdx.x;
  const float* x = s + (size_t)row*CS;
  float v[6]; float sum=0.f, sq=0.f;
  #pragma unroll
  for (int i=0;i<6;i++){ v[i]=x[lane+64*i]; sum+=v[i]; sq+=v[i]*v[i]; }
  #pragma unroll
  for (int off=32; off; off>>=1){ sum+=__shfl_xor(sum,off); sq+=__shfl_xor(sq,off); }
  float m = sum*(1.f/CS);
  float var = sq*(1.f/CS)-m*m;
  float rs = rsqrtf(var+1e-5f);
  #pragma unroll
  for (int i=0;i<6;i++){
    int c = lane+64*i;
    float val = (v[i]-m)*rs*gamma[c];
    __hip_bfloat16 h,l; split2(val,h,l);
    oh[(size_t)row*CS+c]=h; ol[(size_t)row*CS+c]=l;
  }
}

// ---------------- LN(a) -> fp32 ----------------
__global__ __launch_bounds__(64) void ln_a_kernel(const float* __restrict__ a,
                                                  float* __restrict__ out){
  int row = blockIdx.x, lane = threadIdx.x;
  const float* x = a + (size_t)row*CA;
  float v[12]; float sum=0.f, sq=0.f;
  #pragma unroll
  for (int i=0;i<12;i++){ v[i]=x[lane+64*i]; sum+=v[i]; sq+=v[i]*v[i]; }
  #pragma unroll
  for (int off=32; off; off>>=1){ sum+=__shfl_xor(sum,off); sq+=__shfl_xor(sq,off); }
  float m = sum*(1.f/CA);
  float var = sq*(1.f/CA)-m*m;
  float rs = rsqrtf(var+1e-5f);
  float* o = out + (size_t)row*CA;
  #pragma unroll
  for (int i=0;i<12;i++) o[lane+64*i] = (v[i]-m)*rs;
}

// ---------------- plain fp32 -> split bf16 ----------------
__global__ __launch_bounds__(256) void split_kernel(const float* __restrict__ src,
                                                    __hip_bfloat16* __restrict__ dh,
                                                    __hip_bfloat16* __restrict__ dl, int n){
  int i = blockIdx.x*256 + threadIdx.x;
  if (i < n){
    __hip_bfloat16 h,l; split2(src[i],h,l);
    dh[i]=h; dl[i]=l;
  }
}

// ---------------- transpose + split weights: src[K][N] -> dst[N][K] hi/lo ----------------
__global__ __launch_bounds__(256) void cvtT_kernel(const float* __restrict__ src,
                                                   __hip_bfloat16* __restrict__ dh,
                                                   __hip_bfloat16* __restrict__ dl,
                                                   int K, int N){
  __shared__ float tile[64][65];
  int kb = blockIdx.x*64, nb = blockIdx.y*64;
  int tid = threadIdx.x;
  int c = tid & 63, r0 = tid >> 6;
  #pragma unroll
  for (int i=0;i<16;i++){
    int r = r0 + 4*i;
    tile[r][c] = src[(size_t)(kb+r)*N + nb + c];
  }
  __syncthreads();
  #pragma unroll
  for (int i=0;i<16;i++){
    int r = r0 + 4*i;          // n-local
    float x = tile[c][r];      // c = k-local
    __hip_bfloat16 h,l; split2(x,h,l);
    dh[(size_t)(nb+r)*K + kb + c] = h;
    dl[(size_t)(nb+r)*K + kb + c] = l;
  }
}

// ---------------- zbias: bias[(w,q,k), h] = LN(z_row)*gamma @ wz ----------------
// wave handles 32 rows; wz*gamma kept in 32 regs/lane; k-index = part + 4*i (conflict-free broadcast)
__global__ __launch_bounds__(256) void zbias_kernel(const float* __restrict__ z,
                                                    const float* __restrict__ gamma,
                                                    const float* __restrict__ wz,
                                                    float* __restrict__ biasb){
  __shared__ float rowbuf[4][CZ];
  int tid = threadIdx.x;
  int wave = tid >> 6, lane = tid & 63;
  int h = lane & 15, part = lane >> 4;
  float wzreg[32]; float w1 = 0.f;
  #pragma unroll
  for (int i=0;i<32;i++){
    int k = part + 4*i;
    float wv = wz[k*NHEAD + h]*gamma[k];
    wzreg[i] = wv; w1 += wv;
  }
  size_t row0 = (size_t)blockIdx.x*128 + wave*32;
  for (int r=0;r<32;r++){
    size_t row = row0 + r;
    float2 x01 = ((const float2*)(z + row*CZ))[lane];
    float s = x01.x + x01.y, sq = x01.x*x01.x + x01.y*x01.y;
    #pragma unroll
    for (int off=32; off; off>>=1){ s += __shfl_xor(s,off); sq += __shfl_xor(sq,off); }
    float m = s*(1.f/CZ);
    float var = sq*(1.f/CZ) - m*m;
    float rs = rsqrtf(var + 1e-5f);
    ((float2*)rowbuf[wave])[lane] = x01;
    __builtin_amdgcn_s_waitcnt(0);  // lgkm drain before reads (same wave, no barrier needed)
    float partial = 0.f;
    #pragma unroll
    for (int i=0;i<32;i++) partial += rowbuf[wave][part + 4*i]*wzreg[i];
    partial -= m*w1;
    partial += __shfl_xor(partial, 16);
    partial += __shfl_xor(partial, 32);
    if (part == 0) biasb[row*NHEAD + h] = rs*partial;
  }
}

// ---------------- split-bf16 MFMA GEMM ----------------
// C[m][n] = sum_k A[m][k]*Wt[n][k], A given as hi/lo [M][K] bf16, Wt hi/lo [N][K] bf16.
// mode 0: out = acc + bias
// mode 2: out = sigmoid(acc + bias) * aux
__global__ __launch_bounds__(256) void gemm_split(
  const __hip_bfloat16* __restrict__ Ah, const __hip_bfloat16* __restrict__ Al,
  const __hip_bfloat16* __restrict__ Bh, const __hip_bfloat16* __restrict__ Bl,
  const float* __restrict__ bias, const float* __restrict__ aux,
  float* __restrict__ out, int M, int N, int K, int mode)
{
  __shared__ __hip_bfloat16 Ah_s[128*32];
  __shared__ __hip_bfloat16 Al_s[128*32];
  __shared__ __hip_bfloat16 Bh_s[128*32];
  __shared__ __hip_bfloat16 Bl_s[128*32];
  int tid = threadIdx.x;
  int w = tid >> 6, lane = tid & 63;
  int lr = lane & 15, quad = lane >> 4;
  int m0 = blockIdx.y*128, n0 = blockIdx.x*128;
  int mbase = (w&1)*64, nbase = (w>>1)*64;

  float4v acc[4][4];
  #pragma unroll
  for (int i=0;i<4;i++)
    #pragma unroll
    for (int j=0;j<4;j++) acc[i][j] = (float4v){0.f,0.f,0.f,0.f};

  int grow = w*32 + (lane>>2);        // row handled by this lane for staging (0..127 over 2 instrs)
  int gcol8 = (lane&3)*8;             // k element offset

  for (int k0=0; k0<K; k0+=32){
    __syncthreads();
    #pragma unroll
    for (int i=0;i<2;i++){
      int rA = grow + i*16;
      const __hip_bfloat16* gAh = Ah + (size_t)(m0 + rA)*K + k0 + gcol8;
      const __hip_bfloat16* gAl = Al + (size_t)(m0 + rA)*K + k0 + gcol8;
      const __hip_bfloat16* gBh = Bh + (size_t)(n0 + rA)*K + k0 + gcol8;
      const __hip_bfloat16* gBl = Bl + (size_t)(n0 + rA)*K + k0 + gcol8;
      gload_lds16(gAh, &Ah_s[(w*32 + i*16)*32]);
      gload_lds16(gAl, &Al_s[(w*32 + i*16)*32]);
      gload_lds16(gBh, &Bh_s[(w*32 + i*16)*32]);
      gload_lds16(gBl, &Bl_s[(w*32 + i*16)*32]);
    }
    __syncthreads();

    short8 afh[4], afl[4], bfh[4], bfl[4];
    #pragma unroll
    for (int mi=0;mi<4;mi++){
      int off = (mbase + mi*16 + lr)*32 + quad*8;
      afh[mi] = *(const short8*)&Ah_s[off];
      afl[mi] = *(const short8*)&Al_s[off];
    }
    #pragma unroll
    for (int ni=0;ni<4;ni++){
      int off = (nbase + ni*16 + lr)*32 + quad*8;
      bfh[ni] = *(const short8*)&Bh_s[off];
      bfl[ni] = *(const short8*)&Bl_s[off];
    }
    #pragma unroll
    for (int mi=0;mi<4;mi++)
      #pragma unroll
      for (int ni=0;ni<4;ni++){
        acc[mi][ni] = __builtin_amdgcn_mfma_f32_16x16x32_bf16(afh[mi], bfh[ni], acc[mi][ni], 0,0,0);
        acc[mi][ni] = __builtin_amdgcn_mfma_f32_16x16x32_bf16(afh[mi], bfl[ni], acc[mi][ni], 0,0,0);
        acc[mi][ni] = __builtin_amdgcn_mfma_f32_16x16x32_bf16(afl[mi], bfh[ni], acc[mi][ni], 0,0,0);
      }
  }

  #pragma unroll
  for (int ni=0;ni<4;ni++){
    int col = n0 + nbase + ni*16 + lr;
    float bv = bias ? bias[col] : 0.f;
    #pragma unroll
    for (int mi=0;mi<4;mi++){
      #pragma unroll
      for (int reg=0;reg<4;reg++){
        int row = m0 + mbase + mi*16 + quad*4 + reg;
        float v = acc[mi][ni][reg] + bv;
        if (mode == 2) v = sigmoidf_(v)*aux[(size_t)row*N + col];
        out[(size_t)row*N + col] = v;
      }
    }
  }
}

// ---------------- adaln combine: a_ln = sigmoid(t1+bs)*a_n + t2 -> split bf16 ----------------
__global__ __launch_bounds__(256) void adaln_combine(const float* __restrict__ t12,
                                                     const float* __restrict__ a_n,
                                                     const float* __restrict__ bs,
                                                     __hip_bfloat16* __restrict__ ah,
                                                     __hip_bfloat16* __restrict__ al){
  int idx = blockIdx.x*256 + threadIdx.x;   // one float4 per thread
  int r = idx / 192, cq = (idx - r*192)*4;
  float4 t1 = *(const float4*)(t12 + (size_t)r*1536 + cq);
  float4 t2 = *(const float4*)(t12 + (size_t)r*1536 + 768 + cq);
  float4 an = *(const float4*)(a_n + (size_t)r*768 + cq);
  float4 b  = *(const float4*)(bs + cq);
  float v[4] = { sigmoidf_(t1.x+b.x)*an.x + t2.x,
                 sigmoidf_(t1.y+b.y)*an.y + t2.y,
                 sigmoidf_(t1.z+b.z)*an.z + t2.z,
                 sigmoidf_(t1.w+b.w)*an.w + t2.w };
  #pragma unroll
  for (int j=0;j<4;j++){
    __hip_bfloat16 h,l; split2(v[j],h,l);
    ah[(size_t)r*768 + cq + j] = h;
    al[(size_t)r*768 + cq + j] = l;
  }
}

// ---------------- local attention: one block per (w, h) ----------------
// reads packed qkvg [4096][3072] (q|k|v|g), adds bq/bg, sigmoid-gates, writes og hi/lo bf16
__global__ __launch_bounds__(256) void attn_kernel(
  const float* __restrict__ qkvg, const float* __restrict__ bq, const float* __restrict__ bg,
  const float* __restrict__ biasb,
  __hip_bfloat16* __restrict__ ogh, __hip_bfloat16* __restrict__ ogl)
{
  const int w = blockIdx.x, h = blockIdx.y;
  __shared__ float qs[NQW][DH];
  __shared__ float kvs[NKW][DH+1];
  __shared__ float sc[NQW][NKW];
  int tid = threadIdx.x;
  int start = w*NQW - 48;

  for (int idx=tid; idx<NQW*DH; idx+=256){
    int r = idx/DH, d = idx - r*DH;
    qs[r][d] = qkvg[(size_t)(w*NQW+r)*3072 + h*DH + d] + bq[h*DH + d];
  }
  for (int idx=tid; idx<NKW*DH; idx+=256){
    int r = idx/DH, d = idx - r*DH;
    int kr = min(max(start+r,0),N_TOK-1);
    kvs[r][d] = qkvg[(size_t)kr*3072 + 768 + h*DH + d];
  }
  __syncthreads();

  const float scale = 0.14433756729740643f;  // 1/sqrt(48)
  int r = tid >> 3, sub = tid & 7;
  #pragma unroll
  for (int j=0;j<16;j++){
    int k = sub + 8*j;
    float dot = 0.f;
    #pragma unroll
    for (int d=0; d<DH; d++) dot += qs[r][d]*kvs[k][d];
    int kg = start + k;
    float bv = biasb[((size_t)(w*NQW+r)*NKW + k)*NHEAD + h];
    sc[r][k] = (kg>=0 && kg<N_TOK) ? (dot*scale + bv) : -1e9f;
  }
  __syncthreads();

  for (int idx=tid; idx<NKW*DH; idx+=256){
    int rr = idx/DH, d = idx - rr*DH;
    int kr = min(max(start+rr,0),N_TOK-1);
    kvs[rr][d] = qkvg[(size_t)kr*3072 + 1536 + h*DH + d];
  }
  int wave = tid >> 6, lane = tid & 63;
  for (int rr=0; rr<8; rr++){
    int row = wave*8 + rr;
    float v0 = sc[row][lane], v1 = sc[row][lane+64];
    float mx = fmaxf(v0, v1);
    #pragma unroll
    for (int off=32; off; off>>=1) mx = fmaxf(mx, __shfl_xor(mx,off));
    float e0 = __expf(v0-mx), e1 = __expf(v1-mx);
    float sm = e0+e1;
    #pragma unroll
    for (int off=32; off; off>>=1) sm += __shfl_xor(sm,off);
    float inv = 1.f/sm;
    sc[row][lane] = e0*inv; sc[row][lane+64] = e1*inv;
  }
  __syncthreads();

  for (int idx=tid; idx<NQW*DH; idx+=256){
    int rr = idx/DH, d = idx - rr*DH;
    float o = 0.f;
    for (int k=0;k<NKW;k++) o += sc[rr][k]*kvs[k][d];
    size_t row = (size_t)(w*NQW+rr);
    float g = qkvg[row*3072 + 2304 + h*DH + d] + bg[h*DH + d];
    float val = o * sigmoidf_(g);
    __hip_bfloat16 hh,ll; split2(val,hh,ll);
    size_t gi = row*CA + h*DH + d;
    ogh[gi] = hh; ogl[gi] = ll;
  }
}

extern "C" void kernel_launch(void* const* d_in, const int* in_sizes, int n_in,
                              void* d_out, int out_size, void* d_ws, size_t ws_size,
                              hipStream_t stream)
{
  const float* a            = (const float*)d_in[0];
  const float* s            = (const float*)d_in[1];
  const float* z            = (const float*)d_in[2];
  const float* adaln_gamma  = (const float*)d_in[3];
  const float* adaln_ws     = (const float*)d_in[4];
  const float* adaln_bs     = (const float*)d_in[5];
  const float* adaln_wskip  = (const float*)d_in[6];
  const float* lnz_gamma    = (const float*)d_in[7];
  const float* wz           = (const float*)d_in[8];
  const float* wq           = (const float*)d_in[9];
  const float* bq           = (const float*)d_in[10];
  const float* wk           = (const float*)d_in[11];
  const float* wv           = (const float*)d_in[12];
  const float* wg           = (const float*)d_in[13];
  const float* bg           = (const float*)d_in[14];
  const float* wo           = (const float*)d_in[15];
  const float* bo           = (const float*)d_in[16];
  const float* w_last       = (const float*)d_in[17];
  const float* b_last       = (const float*)d_in[18];
  float* out = (float*)d_out;

  // ---- workspace layout (256B-aligned chunks) ----
  char* base = (char*)d_ws;
  size_t off = 0;
  auto alloc = [&](size_t bytes)->char*{ char* p = base + off; off += (bytes + 255) & ~(size_t)255; return p; };

  __hip_bfloat16* s_ln_h = (__hip_bfloat16*)alloc((size_t)N_TOK*CS*2);
  __hip_bfloat16* s_ln_l = (__hip_bfloat16*)alloc((size_t)N_TOK*CS*2);
  __hip_bfloat16* s_h    = (__hip_bfloat16*)alloc((size_t)N_TOK*CS*2);
  __hip_bfloat16* s_l    = (__hip_bfloat16*)alloc((size_t)N_TOK*CS*2);
  float*          a_n    = (float*)alloc((size_t)N_TOK*CA*4);
  __hip_bfloat16* a_ln_h = (__hip_bfloat16*)alloc((size_t)N_TOK*CA*2);
  __hip_bfloat16* a_ln_l = (__hip_bfloat16*)alloc((size_t)N_TOK*CA*2);
  __hip_bfloat16* og_h   = (__hip_bfloat16*)alloc((size_t)N_TOK*CA*2);
  __hip_bfloat16* og_l   = (__hip_bfloat16*)alloc((size_t)N_TOK*CA*2);
  __hip_bfloat16* Wt1_h  = (__hip_bfloat16*)alloc((size_t)1536*CS*2);
  __hip_bfloat16* Wt1_l  = (__hip_bfloat16*)alloc((size_t)1536*CS*2);
  __hip_bfloat16* Wt2_h  = (__hip_bfloat16*)alloc((size_t)3072*CA*2);
  __hip_bfloat16* Wt2_l  = (__hip_bfloat16*)alloc((size_t)3072*CA*2);
  __hip_bfloat16* Wt3_h  = (__hip_bfloat16*)alloc((size_t)CA*CA*2);
  __hip_bfloat16* Wt3_l  = (__hip_bfloat16*)alloc((size_t)CA*CA*2);
  __hip_bfloat16* Wt4_h  = (__hip_bfloat16*)alloc((size_t)CA*CS*2);
  __hip_bfloat16* Wt4_l  = (__hip_bfloat16*)alloc((size_t)CA*CS*2);
  float*          biasb  = (float*)alloc((size_t)NBLK*NQW*NKW*NHEAD*4);
  // big region: t12 [4096][1536] -> reused as qkvg [4096][3072] -> reused as t3 [4096][768]
  float*          big    = (float*)alloc((size_t)N_TOK*3072*4);
  float* t12  = big;
  float* qkvg = big;
  float* t3   = big;

  // ---- LN + conversions ----
  ln_s_kernel<<<dim3(N_TOK), dim3(64), 0, stream>>>(s, adaln_gamma, s_ln_h, s_ln_l);
  ln_a_kernel<<<dim3(N_TOK), dim3(64), 0, stream>>>(a, a_n);
  split_kernel<<<dim3((N_TOK*CS)/256), 256, 0, stream>>>(s, s_h, s_l, N_TOK*CS);

  cvtT_kernel<<<dim3(CS/64, CA/64), 256, 0, stream>>>(adaln_ws,    Wt1_h,             Wt1_l,             CS, CA);
  cvtT_kernel<<<dim3(CS/64, CA/64), 256, 0, stream>>>(adaln_wskip, Wt1_h + 768*CS,    Wt1_l + 768*CS,    CS, CA);
  cvtT_kernel<<<dim3(CA/64, CA/64), 256, 0, stream>>>(wq,          Wt2_h,             Wt2_l,             CA, CA);
  cvtT_kernel<<<dim3(CA/64, CA/64), 256, 0, stream>>>(wk,          Wt2_h + 768*CA,    Wt2_l + 768*CA,    CA, CA);
  cvtT_kernel<<<dim3(CA/64, CA/64), 256, 0, stream>>>(wv,          Wt2_h + 1536*CA,   Wt2_l + 1536*CA,   CA, CA);
  cvtT_kernel<<<dim3(CA/64, CA/64), 256, 0, stream>>>(wg,          Wt2_h + 2304*CA,   Wt2_l + 2304*CA,   CA, CA);
  cvtT_kernel<<<dim3(CA/64, CA/64), 256, 0, stream>>>(wo,          Wt3_h,             Wt3_l,             CA, CA);
  cvtT_kernel<<<dim3(CS/64, CA/64), 256, 0, stream>>>(w_last,      Wt4_h,             Wt4_l,             CS, CA);

  // ---- z bias ----
  zbias_kernel<<<dim3((NBLK*NQW*NKW)/128), 256, 0, stream>>>(z, lnz_gamma, wz, biasb);

  // ---- adaln: t12 = s_ln @ [ws|wskip] ----
  gemm_split<<<dim3(1536/128, N_TOK/128), 256, 0, stream>>>(
      s_ln_h, s_ln_l, Wt1_h, Wt1_l, nullptr, nullptr, t12, N_TOK, 1536, CS, 0);
  adaln_combine<<<dim3((N_TOK*192)/256), 256, 0, stream>>>(t12, a_n, adaln_bs, a_ln_h, a_ln_l);

  // ---- qkvg = a_ln @ [wq|wk|wv|wg] (biases folded in attn) ----
  gemm_split<<<dim3(3072/128, N_TOK/128), 256, 0, stream>>>(
      a_ln_h, a_ln_l, Wt2_h, Wt2_l, nullptr, nullptr, qkvg, N_TOK, 3072, CA, 0);

  // ---- attention ----
  attn_kernel<<<dim3(NBLK, NHEAD), 256, 0, stream>>>(qkvg, bq, bg, biasb, og_h, og_l);

  // ---- t3 = og @ wo + bo ----
  gemm_split<<<dim3(CA/128, N_TOK/128), 256, 0, stream>>>(
      og_h, og_l, Wt3_h, Wt3_l, bo, nullptr, t3, N_TOK, CA, CA, 0);

  // ---- out = sigmoid(s @ w_last + b_last) * t3 ----
  gemm_split<<<dim3(CA/128, N_TOK/128), 256, 0, stream>>>(
      s_h, s_l, Wt4_h, Wt4_l, b_last, t3, out, N_TOK, CA, CS, 2);
}

// Round 3
// 731.309 us; speedup vs baseline: 1.7377x; 1.1613x over previous
//
#include <hip/hip_runtime.h>
#include <hip/hip_bf16.h>
#include <math.h>

#define N_TOK 4096
#define CA 768
#define CS 384
#define CZ 128
#define NHEAD 16
#define DH 48
#define NQW 32
#define NKW 128
#define NBLK 128

typedef __attribute__((ext_vector_type(8))) short short8;
typedef __attribute__((ext_vector_type(4))) float float4v;
typedef __attribute__((ext_vector_type(4))) unsigned int uint4v;

__device__ __forceinline__ float sigmoidf_(float x){ return 1.0f/(1.0f+__expf(-x)); }

__device__ __forceinline__ unsigned short f2bf(float x){
  unsigned u = __float_as_uint(x);
  unsigned r = (u + 0x7FFFu + ((u>>16)&1u)) >> 16;
  return (unsigned short)r;
}
__device__ __forceinline__ float bf2f(unsigned short b){
  return __uint_as_float(((unsigned)b)<<16);
}
__device__ __forceinline__ void split1(float x, unsigned short& h, unsigned short& l){
  h = f2bf(x);
  l = f2bf(x - bf2f(h));
}
__device__ __forceinline__ void split8(const float* xv, short8& hi, short8& lo){
  union { short8 v; unsigned short u[8]; } H, L;
  #pragma unroll
  for (int j=0;j<8;j++){
    unsigned short h = f2bf(xv[j]);
    H.u[j] = h;
    L.u[j] = f2bf(xv[j] - bf2f(h));
  }
  hi = H.v; lo = L.v;
}

__device__ __forceinline__ void gload_lds16(const void* gsrc, void* ldst){
  __builtin_amdgcn_global_load_lds(
    (const __attribute__((address_space(1))) void*)gsrc,
    (__attribute__((address_space(3))) void*)ldst, 16, 0, 0);
}

// ---------------- LN(s)*gamma -> split bf16 planes ----------------
__global__ __launch_bounds__(64) void ln_s_kernel(const float* __restrict__ s,
                                                  const float* __restrict__ gamma,
                                                  unsigned short* __restrict__ oh,
                                                  unsigned short* __restrict__ ol){
  int row = blockIdx.x, lane = threadIdx.x;
  const float* x = s + (size_t)row*CS;
  float v[6]; float sum=0.f, sq=0.f;
  #pragma unroll
  for (int i=0;i<6;i++){ v[i]=x[lane+64*i]; sum+=v[i]; sq+=v[i]*v[i]; }
  #pragma unroll
  for (int off=32; off; off>>=1){ sum+=__shfl_xor(sum,off); sq+=__shfl_xor(sq,off); }
  float m = sum*(1.f/CS);
  float var = sq*(1.f/CS)-m*m;
  float rs = rsqrtf(var+1e-5f);
  #pragma unroll
  for (int i=0;i<6;i++){
    int c = lane+64*i;
    float val = (v[i]-m)*rs*gamma[c];
    unsigned short h,l; split1(val,h,l);
    oh[(size_t)row*CS+c]=h; ol[(size_t)row*CS+c]=l;
  }
}

// ---------------- LN(a) -> fp32 ----------------
__global__ __launch_bounds__(64) void ln_a_kernel(const float* __restrict__ a,
                                                  float* __restrict__ out){
  int row = blockIdx.x, lane = threadIdx.x;
  const float* x = a + (size_t)row*CA;
  float v[12]; float sum=0.f, sq=0.f;
  #pragma unroll
  for (int i=0;i<12;i++){ v[i]=x[lane+64*i]; sum+=v[i]; sq+=v[i]*v[i]; }
  #pragma unroll
  for (int off=32; off; off>>=1){ sum+=__shfl_xor(sum,off); sq+=__shfl_xor(sq,off); }
  float m = sum*(1.f/CA);
  float var = sq*(1.f/CA)-m*m;
  float rs = rsqrtf(var+1e-5f);
  float* o = out + (size_t)row*CA;
  #pragma unroll
  for (int i=0;i<12;i++) o[lane+64*i] = (v[i]-m)*rs;
}

// ---------------- plain fp32 -> split bf16 planes ----------------
__global__ __launch_bounds__(256) void split_kernel(const float* __restrict__ src,
                                                    unsigned short* __restrict__ dh,
                                                    unsigned short* __restrict__ dl, int n){
  int i = blockIdx.x*256 + threadIdx.x;
  if (i < n){
    unsigned short h,l; split1(src[i],h,l);
    dh[i]=h; dl[i]=l;
  }
}

// ---------------- transpose + split weights: src[K][N] -> dst[N][K] hi/lo ----------------
__global__ __launch_bounds__(256) void cvtT_kernel(const float* __restrict__ src,
                                                   unsigned short* __restrict__ dh,
                                                   unsigned short* __restrict__ dl,
                                                   int K, int N){
  __shared__ float tile[64][65];
  int kb = blockIdx.x*64, nb = blockIdx.y*64;
  int tid = threadIdx.x;
  int c = tid & 63, r0 = tid >> 6;
  #pragma unroll
  for (int i=0;i<16;i++){
    int r = r0 + 4*i;
    tile[r][c] = src[(size_t)(kb+r)*N + nb + c];
  }
  __syncthreads();
  #pragma unroll
  for (int i=0;i<16;i++){
    int r = r0 + 4*i;          // n-local
    float x = tile[c][r];      // c = k-local
    unsigned short h,l; split1(x,h,l);
    dh[(size_t)(nb+r)*K + kb + c] = h;
    dl[(size_t)(nb+r)*K + kb + c] = l;
  }
}

// ---------------- zbias v3 (MFMA): bias3[wq][h][k] = LN(z_row)*gamma @ wz ----------------
// wave processes one 128-row group (= one (w,q)); 8 batches of 16 rows;
// A-frags loaded directly from global in frag layout, LN folded into epilogue.
__global__ __launch_bounds__(256) void zbias_kernel(const float* __restrict__ z,
                                                    const float* __restrict__ gamma,
                                                    const float* __restrict__ wz,
                                                    float* __restrict__ bias3){
  __shared__ float tbuf[4][16*132];
  int tid = threadIdx.x, wave = tid>>6, lane = tid&63;
  int lr = lane&15, quad = lane>>4;

  // weight B-frags: lane lr = h; k = ks*32 + quad*8 + j
  short8 bwh[4], bwl[4];
  float w1 = 0.f;
  #pragma unroll
  for (int ks=0;ks<4;ks++){
    float wv[8];
    #pragma unroll
    for (int j=0;j<8;j++){
      int k = ks*32 + quad*8 + j;
      wv[j] = wz[k*NHEAD + lr]*gamma[k];
      w1 += wv[j];
    }
    split8(wv, bwh[ks], bwl[ks]);
  }
  w1 += __shfl_xor(w1, 16);
  w1 += __shfl_xor(w1, 32);

  size_t group = (size_t)blockIdx.x*4 + wave;   // = w*32+q, 0..4095
  const float* zg = z + group*(size_t)(NKW*CZ);

  #pragma unroll 1
  for (int b=0;b<8;b++){
    int row = b*16 + lr;
    const float* zr = zg + (size_t)row*CZ;
    float x[4][8];
    float sum=0.f, sq=0.f;
    #pragma unroll
    for (int ks=0;ks<4;ks++){
      float4 p0 = *(const float4*)(zr + ks*32 + quad*8);
      float4 p1 = *(const float4*)(zr + ks*32 + quad*8 + 4);
      x[ks][0]=p0.x; x[ks][1]=p0.y; x[ks][2]=p0.z; x[ks][3]=p0.w;
      x[ks][4]=p1.x; x[ks][5]=p1.y; x[ks][6]=p1.z; x[ks][7]=p1.w;
      #pragma unroll
      for (int j=0;j<8;j++){ sum += x[ks][j]; sq += x[ks][j]*x[ks][j]; }
    }
    sum += __shfl_xor(sum,16); sum += __shfl_xor(sum,32);
    sq  += __shfl_xor(sq,16);  sq  += __shfl_xor(sq,32);
    float mean = sum*(1.f/CZ);
    float var = sq*(1.f/CZ) - mean*mean;
    float rs = rsqrtf(var + 1e-5f);

    float4v c = (float4v){0.f,0.f,0.f,0.f};
    #pragma unroll
    for (int ks=0;ks<4;ks++){
      short8 ah, al;
      split8(x[ks], ah, al);
      c = __builtin_amdgcn_mfma_f32_16x16x32_bf16(ah, bwh[ks], c, 0,0,0);
      c = __builtin_amdgcn_mfma_f32_16x16x32_bf16(ah, bwl[ks], c, 0,0,0);
      c = __builtin_amdgcn_mfma_f32_16x16x32_bf16(al, bwh[ks], c, 0,0,0);
    }
    // epilogue: C col=lane&15=h, row=quad*4+reg = k within batch
    #pragma unroll
    for (int r=0;r<4;r++){
      int rrow = quad*4 + r;
      float m_r  = __shfl(mean, rrow);
      float rs_r = __shfl(rs, rrow);
      float val = rs_r*(c[r] - m_r*w1);
      tbuf[wave][lr*132 + b*16 + rrow] = val;
    }
  }
  // coalesced store: bias3[group][h][k]
  #pragma unroll
  for (int i=0;i<8;i++){
    int h = i*2 + (lane>>5);
    int koff = (lane&31)*4;
    float4 vv = *(const float4*)&tbuf[wave][h*132 + koff];
    *(float4*)(bias3 + group*2048 + h*128 + koff) = vv;
  }
}

// ---------------- split-bf16 MFMA GEMM ----------------
// C[m][n] = sum_k A[m][k]*Wt[n][k].
// A either split planes (Ah/Al, packA=0) or packed u32 hi<<16|lo (Apk, packA=1).
// mode 0: out = acc + bias ; mode 2: out = sigmoid(acc + bias) * aux
__global__ __launch_bounds__(256) void gemm_split(
  const unsigned short* __restrict__ Ah, const unsigned short* __restrict__ Al,
  const unsigned int* __restrict__ Apk, int packA,
  const unsigned short* __restrict__ Bh, const unsigned short* __restrict__ Bl,
  const float* __restrict__ bias, const float* __restrict__ aux,
  float* __restrict__ out, int M, int N, int K, int mode)
{
  __shared__ unsigned int As_u[128*32];        // 16 KB: packed u32, or hi plane + lo plane
  __shared__ unsigned short Bh_s[128*32];
  __shared__ unsigned short Bl_s[128*32];
  unsigned short* Ah_s = (unsigned short*)As_u;          // split path hi plane
  unsigned short* Al_s = (unsigned short*)As_u + 128*32; // split path lo plane

  int tid = threadIdx.x;
  int w = tid >> 6, lane = tid & 63;
  int lr = lane & 15, quad = lane >> 4;
  int m0 = blockIdx.y*128, n0 = blockIdx.x*128;
  int mbase = (w&1)*64, nbase = (w>>1)*64;

  float4v acc[4][4];
  #pragma unroll
  for (int i=0;i<4;i++)
    #pragma unroll
    for (int j=0;j<4;j++) acc[i][j] = (float4v){0.f,0.f,0.f,0.f};

  int grow = w*32 + (lane>>2);
  int gcol8 = (lane&3)*8;
  int prow = (lane>>3);
  int pcol4 = (lane&7)*4;

  for (int k0=0; k0<K; k0+=32){
    __syncthreads();
    if (packA){
      #pragma unroll
      for (int i=0;i<4;i++){
        int r = w*32 + i*8;
        gload_lds16(Apk + (size_t)(m0 + r + prow)*K + k0 + pcol4, &As_u[r*32]);
      }
    } else {
      #pragma unroll
      for (int i=0;i<2;i++){
        int rA = grow + i*16;
        gload_lds16(Ah + (size_t)(m0 + rA)*K + k0 + gcol8, &Ah_s[(w*32 + i*16)*32]);
        gload_lds16(Al + (size_t)(m0 + rA)*K + k0 + gcol8, &Al_s[(w*32 + i*16)*32]);
      }
    }
    #pragma unroll
    for (int i=0;i<2;i++){
      int rA = grow + i*16;
      gload_lds16(Bh + (size_t)(n0 + rA)*K + k0 + gcol8, &Bh_s[(w*32 + i*16)*32]);
      gload_lds16(Bl + (size_t)(n0 + rA)*K + k0 + gcol8, &Bl_s[(w*32 + i*16)*32]);
    }
    __syncthreads();

    short8 afh[4], afl[4], bfh[4], bfl[4];
    if (packA){
      #pragma unroll
      for (int mi=0;mi<4;mi++){
        int off = (mbase + mi*16 + lr)*32 + quad*8;
        uint4v u0 = *(const uint4v*)&As_u[off];
        uint4v u1 = *(const uint4v*)&As_u[off+4];
        uint4v hv, lv;
        hv.x = __builtin_amdgcn_perm(u0.y, u0.x, 0x07060302u);
        hv.y = __builtin_amdgcn_perm(u0.w, u0.z, 0x07060302u);
        hv.z = __builtin_amdgcn_perm(u1.y, u1.x, 0x07060302u);
        hv.w = __builtin_amdgcn_perm(u1.w, u1.z, 0x07060302u);
        lv.x = __builtin_amdgcn_perm(u0.y, u0.x, 0x05040100u);
        lv.y = __builtin_amdgcn_perm(u0.w, u0.z, 0x05040100u);
        lv.z = __builtin_amdgcn_perm(u1.y, u1.x, 0x05040100u);
        lv.w = __builtin_amdgcn_perm(u1.w, u1.z, 0x05040100u);
        afh[mi] = __builtin_bit_cast(short8, hv);
        afl[mi] = __builtin_bit_cast(short8, lv);
      }
    } else {
      #pragma unroll
      for (int mi=0;mi<4;mi++){
        int off = (mbase + mi*16 + lr)*32 + quad*8;
        afh[mi] = *(const short8*)&Ah_s[off];
        afl[mi] = *(const short8*)&Al_s[off];
      }
    }
    #pragma unroll
    for (int ni=0;ni<4;ni++){
      int off = (nbase + ni*16 + lr)*32 + quad*8;
      bfh[ni] = *(const short8*)&Bh_s[off];
      bfl[ni] = *(const short8*)&Bl_s[off];
    }
    #pragma unroll
    for (int mi=0;mi<4;mi++)
      #pragma unroll
      for (int ni=0;ni<4;ni++){
        acc[mi][ni] = __builtin_amdgcn_mfma_f32_16x16x32_bf16(afh[mi], bfh[ni], acc[mi][ni], 0,0,0);
        acc[mi][ni] = __builtin_amdgcn_mfma_f32_16x16x32_bf16(afh[mi], bfl[ni], acc[mi][ni], 0,0,0);
        acc[mi][ni] = __builtin_amdgcn_mfma_f32_16x16x32_bf16(afl[mi], bfh[ni], acc[mi][ni], 0,0,0);
      }
  }

  #pragma unroll
  for (int ni=0;ni<4;ni++){
    int col = n0 + nbase + ni*16 + lr;
    float bv = bias ? bias[col] : 0.f;
    #pragma unroll
    for (int mi=0;mi<4;mi++){
      #pragma unroll
      for (int reg=0;reg<4;reg++){
        int row = m0 + mbase + mi*16 + quad*4 + reg;
        float v = acc[mi][ni][reg] + bv;
        if (mode == 2) v = sigmoidf_(v)*aux[(size_t)row*N + col];
        out[(size_t)row*N + col] = v;
      }
    }
  }
}

// ---------------- adaln combine: a_ln = sigmoid(t1+bs)*a_n + t2 -> split planes ----------------
__global__ __launch_bounds__(256) void adaln_combine(const float* __restrict__ t12,
                                                     const float* __restrict__ a_n,
                                                     const float* __restrict__ bs,
                                                     unsigned short* __restrict__ ah,
                                                     unsigned short* __restrict__ al){
  int idx = blockIdx.x*256 + threadIdx.x;
  int r = idx / 192, cq = (idx - r*192)*4;
  float4 t1 = *(const float4*)(t12 + (size_t)r*1536 + cq);
  float4 t2 = *(const float4*)(t12 + (size_t)r*1536 + 768 + cq);
  float4 an = *(const float4*)(a_n + (size_t)r*768 + cq);
  float4 b  = *(const float4*)(bs + cq);
  float v[4] = { sigmoidf_(t1.x+b.x)*an.x + t2.x,
                 sigmoidf_(t1.y+b.y)*an.y + t2.y,
                 sigmoidf_(t1.z+b.z)*an.z + t2.z,
                 sigmoidf_(t1.w+b.w)*an.w + t2.w };
  #pragma unroll
  for (int j=0;j<4;j++){
    unsigned short h,l; split1(v[j],h,l);
    ah[(size_t)r*768 + cq + j] = h;
    al[(size_t)r*768 + cq + j] = l;
  }
}

// ---------------- attention v3: one wave per (w,h), MFMA, register softmax ----------------
// Q/K/V frags loaded from global qkvg [4096][3072] (q|k|v|g) with in-reg split.
// Output: og packed u32 (hi<<16|lo) [4096][768], gated.
__global__ __launch_bounds__(256) void attn_kernel(
  const float* __restrict__ qkvg, const float* __restrict__ bq, const float* __restrict__ bg,
  const float* __restrict__ bias3, unsigned int* __restrict__ og)
{
  __shared__ unsigned short Pb[4][2][32*72];  // per wave: hi/lo planes, 32 q x 64 keys (pitch 72)
  int tid = threadIdx.x, wave = tid>>6, lane = tid&63;
  int lr = lane&15, quad = lane>>4;
  int w = blockIdx.x, h = blockIdx.y*4 + wave;
  int start = w*NQW - 48;
  const float scale = 0.14433756729740643f;  // 1/sqrt(48)

  // ---- Q A-frags: m=lane&15 -> q row; k = ks*32 + quad*8 + j (d, pad 48->64) ----
  short8 aqh[2][2], aql[2][2];
  #pragma unroll
  for (int mt=0;mt<2;mt++){
    int row = w*NQW + mt*16 + lr;
    #pragma unroll
    for (int ks=0;ks<2;ks++){
      float xv[8];
      if (ks==1 && quad>=2){
        #pragma unroll
        for (int j=0;j<8;j++) xv[j]=0.f;
      } else {
        const float* qp = qkvg + (size_t)row*3072 + h*DH + ks*32 + quad*8;
        const float* bp = bq + h*DH + ks*32 + quad*8;
        float4 a0 = *(const float4*)qp, a1 = *(const float4*)(qp+4);
        float4 b0 = *(const float4*)bp, b1 = *(const float4*)(bp+4);
        xv[0]=a0.x+b0.x; xv[1]=a0.y+b0.y; xv[2]=a0.z+b0.z; xv[3]=a0.w+b0.w;
        xv[4]=a1.x+b1.x; xv[5]=a1.y+b1.y; xv[6]=a1.z+b1.z; xv[7]=a1.w+b1.w;
      }
      split8(xv, aqh[mt][ks], aql[mt][ks]);
    }
  }

  // ---- QK^T ----
  float4v c[2][8];
  #pragma unroll
  for (int mt=0;mt<2;mt++)
    #pragma unroll
    for (int nt=0;nt<8;nt++) c[mt][nt] = (float4v){0.f,0.f,0.f,0.f};

  #pragma unroll 1
  for (int nt=0;nt<8;nt++){
    int krow = start + nt*16 + lr;
    int krc = min(max(krow,0),N_TOK-1);
    short8 bkh[2], bkl[2];
    #pragma unroll
    for (int ks=0;ks<2;ks++){
      float xv[8];
      if (ks==1 && quad>=2){
        #pragma unroll
        for (int j=0;j<8;j++) xv[j]=0.f;
      } else {
        const float* kp = qkvg + (size_t)krc*3072 + 768 + h*DH + ks*32 + quad*8;
        float4 a0 = *(const float4*)kp, a1 = *(const float4*)(kp+4);
        xv[0]=a0.x; xv[1]=a0.y; xv[2]=a0.z; xv[3]=a0.w;
        xv[4]=a1.x; xv[5]=a1.y; xv[6]=a1.z; xv[7]=a1.w;
      }
      split8(xv, bkh[ks], bkl[ks]);
    }
    #pragma unroll
    for (int mt=0;mt<2;mt++){
      #pragma unroll
      for (int ks=0;ks<2;ks++){
        c[mt][nt] = __builtin_amdgcn_mfma_f32_16x16x32_bf16(aqh[mt][ks], bkh[ks], c[mt][nt], 0,0,0);
        c[mt][nt] = __builtin_amdgcn_mfma_f32_16x16x32_bf16(aqh[mt][ks], bkl[ks], c[mt][nt], 0,0,0);
        c[mt][nt] = __builtin_amdgcn_mfma_f32_16x16x32_bf16(aql[mt][ks], bkh[ks], c[mt][nt], 0,0,0);
      }
    }
  }

  // ---- bias + mask + softmax in registers (C: col=key=nt*16+lr, row=quad*4+reg) ----
  float rmax[2][4], rsum[2][4];
  #pragma unroll
  for (int mt=0;mt<2;mt++)
    #pragma unroll
    for (int r=0;r<4;r++){ rmax[mt][r] = -3.0e38f; rsum[mt][r] = 0.f; }

  #pragma unroll
  for (int nt=0;nt<8;nt++){
    int key = start + nt*16 + lr;
    bool valid = (key>=0) && (key<N_TOK);
    #pragma unroll
    for (int mt=0;mt<2;mt++){
      #pragma unroll
      for (int r=0;r<4;r++){
        int q = mt*16 + quad*4 + r;
        float bv = bias3[(((size_t)(w*NQW+q))*NHEAD + h)*128 + nt*16 + lr];
        float v = valid ? (c[mt][nt][r]*scale + bv) : -1e9f;
        c[mt][nt][r] = v;
        rmax[mt][r] = fmaxf(rmax[mt][r], v);
      }
    }
  }
  #pragma unroll
  for (int mt=0;mt<2;mt++)
    #pragma unroll
    for (int r=0;r<4;r++){
      float m = rmax[mt][r];
      m = fmaxf(m, __shfl_xor(m,1)); m = fmaxf(m, __shfl_xor(m,2));
      m = fmaxf(m, __shfl_xor(m,4)); m = fmaxf(m, __shfl_xor(m,8));
      rmax[mt][r] = m;
    }
  #pragma unroll
  for (int nt=0;nt<8;nt++)
    #pragma unroll
    for (int mt=0;mt<2;mt++)
      #pragma unroll
      for (int r=0;r<4;r++){
        float e = __expf(c[mt][nt][r] - rmax[mt][r]);
        c[mt][nt][r] = e;
        rsum[mt][r] += e;
      }
  #pragma unroll
  for (int mt=0;mt<2;mt++)
    #pragma unroll
    for (int r=0;r<4;r++){
      float sv = rsum[mt][r];
      sv += __shfl_xor(sv,1); sv += __shfl_xor(sv,2);
      sv += __shfl_xor(sv,4); sv += __shfl_xor(sv,8);
      rsum[mt][r] = 1.f/sv;
    }

  // ---- PV: P through LDS (A-layout), V B-frags from global ----
  unsigned short* ph = &Pb[wave][0][0];
  unsigned short* pl = &Pb[wave][1][0];
  float4v o[2][3];
  #pragma unroll
  for (int mt=0;mt<2;mt++)
    #pragma unroll
    for (int no=0;no<3;no++) o[mt][no] = (float4v){0.f,0.f,0.f,0.f};

  #pragma unroll 1
  for (int c2=0;c2<2;c2++){
    #pragma unroll
    for (int nt4=0;nt4<4;nt4++){
      int nt = c2*4 + nt4;
      #pragma unroll
      for (int mt=0;mt<2;mt++){
        #pragma unroll
        for (int r=0;r<4;r++){
          int q = mt*16 + quad*4 + r;
          float p = c[mt][nt][r]*rsum[mt][r];
          unsigned short hh, ll; split1(p, hh, ll);
          ph[q*72 + nt4*16 + lr] = hh;
          pl[q*72 + nt4*16 + lr] = ll;
        }
      }
    }
    #pragma unroll 1
    for (int ks=0;ks<2;ks++){
      short8 pah[2], pal[2];
      #pragma unroll
      for (int mt=0;mt<2;mt++){
        pah[mt] = *(const short8*)&ph[(mt*16+lr)*72 + ks*32 + quad*8];
        pal[mt] = *(const short8*)&pl[(mt*16+lr)*72 + ks*32 + quad*8];
      }
      #pragma unroll
      for (int no=0;no<3;no++){
        int d = no*16 + lr;
        float xv[8];
        #pragma unroll
        for (int j=0;j<8;j++){
          int key = c2*64 + ks*32 + quad*8 + j;
          int kr = min(max(start+key,0),N_TOK-1);
          xv[j] = qkvg[(size_t)kr*3072 + 1536 + h*DH + d];
        }
        short8 bvh, bvl;
        split8(xv, bvh, bvl);
        #pragma unroll
        for (int mt=0;mt<2;mt++){
          o[mt][no] = __builtin_amdgcn_mfma_f32_16x16x32_bf16(pah[mt], bvh, o[mt][no], 0,0,0);
          o[mt][no] = __builtin_amdgcn_mfma_f32_16x16x32_bf16(pah[mt], bvl, o[mt][no], 0,0,0);
          o[mt][no] = __builtin_amdgcn_mfma_f32_16x16x32_bf16(pal[mt], bvh, o[mt][no], 0,0,0);
        }
      }
    }
  }

  // ---- epilogue: gate + pack ----
  #pragma unroll
  for (int mt=0;mt<2;mt++){
    #pragma unroll
    for (int no=0;no<3;no++){
      int d = no*16 + lr;
      #pragma unroll
      for (int r=0;r<4;r++){
        int q = mt*16 + quad*4 + r;
        size_t grow = (size_t)(w*NQW + q);
        float g = qkvg[grow*3072 + 2304 + h*DH + d] + bg[h*DH + d];
        float val = o[mt][no][r] * sigmoidf_(g);
        unsigned short hh, ll; split1(val, hh, ll);
        og[grow*CA + h*DH + d] = (((unsigned)hh)<<16) | (unsigned)ll;
      }
    }
  }
}

extern "C" void kernel_launch(void* const* d_in, const int* in_sizes, int n_in,
                              void* d_out, int out_size, void* d_ws, size_t ws_size,
                              hipStream_t stream)
{
  const float* a            = (const float*)d_in[0];
  const float* s            = (const float*)d_in[1];
  const float* z            = (const float*)d_in[2];
  const float* adaln_gamma  = (const float*)d_in[3];
  const float* adaln_ws     = (const float*)d_in[4];
  const float* adaln_bs     = (const float*)d_in[5];
  const float* adaln_wskip  = (const float*)d_in[6];
  const float* lnz_gamma    = (const float*)d_in[7];
  const float* wz           = (const float*)d_in[8];
  const float* wq           = (const float*)d_in[9];
  const float* bq           = (const float*)d_in[10];
  const float* wk           = (const float*)d_in[11];
  const float* wv           = (const float*)d_in[12];
  const float* wg           = (const float*)d_in[13];
  const float* bg           = (const float*)d_in[14];
  const float* wo           = (const float*)d_in[15];
  const float* bo           = (const float*)d_in[16];
  const float* w_last       = (const float*)d_in[17];
  const float* b_last       = (const float*)d_in[18];
  float* out = (float*)d_out;

  char* base = (char*)d_ws;
  size_t off = 0;
  auto alloc = [&](size_t bytes)->char*{ char* p = base + off; off += (bytes + 255) & ~(size_t)255; return p; };

  unsigned short* s_ln_h = (unsigned short*)alloc((size_t)N_TOK*CS*2);
  unsigned short* s_ln_l = (unsigned short*)alloc((size_t)N_TOK*CS*2);
  unsigned short* s_h    = (unsigned short*)alloc((size_t)N_TOK*CS*2);
  unsigned short* s_l    = (unsigned short*)alloc((size_t)N_TOK*CS*2);
  float*          a_n    = (float*)alloc((size_t)N_TOK*CA*4);
  unsigned short* a_ln_h = (unsigned short*)alloc((size_t)N_TOK*CA*2);
  unsigned short* a_ln_l = (unsigned short*)alloc((size_t)N_TOK*CA*2);
  unsigned int*   og     = (unsigned int*)alloc((size_t)N_TOK*CA*4);
  unsigned short* Wt1_h  = (unsigned short*)alloc((size_t)1536*CS*2);
  unsigned short* Wt1_l  = (unsigned short*)alloc((size_t)1536*CS*2);
  unsigned short* Wt2_h  = (unsigned short*)alloc((size_t)3072*CA*2);
  unsigned short* Wt2_l  = (unsigned short*)alloc((size_t)3072*CA*2);
  unsigned short* Wt3_h  = (unsigned short*)alloc((size_t)CA*CA*2);
  unsigned short* Wt3_l  = (unsigned short*)alloc((size_t)CA*CA*2);
  unsigned short* Wt4_h  = (unsigned short*)alloc((size_t)CA*CS*2);
  unsigned short* Wt4_l  = (unsigned short*)alloc((size_t)CA*CS*2);
  float*          bias3  = (float*)alloc((size_t)N_TOK*NHEAD*NKW*4);   // [wq][h][k]
  float*          big    = (float*)alloc((size_t)N_TOK*3072*4);
  float* t12  = big;   // [4096][1536]
  float* qkvg = big;   // [4096][3072]
  float* t3   = big;   // [4096][768]

  ln_s_kernel<<<dim3(N_TOK), dim3(64), 0, stream>>>(s, adaln_gamma, s_ln_h, s_ln_l);
  ln_a_kernel<<<dim3(N_TOK), dim3(64), 0, stream>>>(a, a_n);
  split_kernel<<<dim3((N_TOK*CS)/256), 256, 0, stream>>>(s, s_h, s_l, N_TOK*CS);

  cvtT_kernel<<<dim3(CS/64, CA/64), 256, 0, stream>>>(adaln_ws,    Wt1_h,           Wt1_l,           CS, CA);
  cvtT_kernel<<<dim3(CS/64, CA/64), 256, 0, stream>>>(adaln_wskip, Wt1_h + 768*CS,  Wt1_l + 768*CS,  CS, CA);
  cvtT_kernel<<<dim3(CA/64, CA/64), 256, 0, stream>>>(wq,          Wt2_h,           Wt2_l,           CA, CA);
  cvtT_kernel<<<dim3(CA/64, CA/64), 256, 0, stream>>>(wk,          Wt2_h + 768*CA,  Wt2_l + 768*CA,  CA, CA);
  cvtT_kernel<<<dim3(CA/64, CA/64), 256, 0, stream>>>(wv,          Wt2_h + 1536*CA, Wt2_l + 1536*CA, CA, CA);
  cvtT_kernel<<<dim3(CA/64, CA/64), 256, 0, stream>>>(wg,          Wt2_h + 2304*CA, Wt2_l + 2304*CA, CA, CA);
  cvtT_kernel<<<dim3(CA/64, CA/64), 256, 0, stream>>>(wo,          Wt3_h,           Wt3_l,           CA, CA);
  cvtT_kernel<<<dim3(CS/64, CA/64), 256, 0, stream>>>(w_last,      Wt4_h,           Wt4_l,           CS, CA);

  zbias_kernel<<<dim3(N_TOK/4), 256, 0, stream>>>(z, lnz_gamma, wz, bias3);

  gemm_split<<<dim3(1536/128, N_TOK/128), 256, 0, stream>>>(
      s_ln_h, s_ln_l, nullptr, 0, Wt1_h, Wt1_l, nullptr, nullptr, t12, N_TOK, 1536, CS, 0);
  adaln_combine<<<dim3((N_TOK*192)/256), 256, 0, stream>>>(t12, a_n, adaln_bs, a_ln_h, a_ln_l);

  gemm_split<<<dim3(3072/128, N_TOK/128), 256, 0, stream>>>(
      a_ln_h, a_ln_l, nullptr, 0, Wt2_h, Wt2_l, nullptr, nullptr, qkvg, N_TOK, 3072, CA, 0);

  attn_kernel<<<dim3(NBLK, 4), 256, 0, stream>>>(qkvg, bq, bg, bias3, og);

  gemm_split<<<dim3(CA/128, N_TOK/128), 256, 0, stream>>>(
      nullptr, nullptr, og, 1, Wt3_h, Wt3_l, bo, nullptr, t3, N_TOK, CA, CA, 0);

  gemm_split<<<dim3(CA/128, N_TOK/128), 256, 0, stream>>>(
      s_h, s_l, nullptr, 0, Wt4_h, Wt4_l, b_last, t3, out, N_TOK, CA, CS, 2);
}

// Round 4
// 633.156 us; speedup vs baseline: 2.0071x; 1.1550x over previous
//
#include <hip/hip_runtime.h>
#include <hip/hip_bf16.h>
#include <math.h>

#define N_TOK 4096
#define CA 768
#define CS 384
#define CZ 128
#define NHEAD 16
#define DH 48
#define NQW 32
#define NKW 128
#define NBLK 128

typedef __attribute__((ext_vector_type(8))) short short8;
typedef __attribute__((ext_vector_type(4))) float float4v;

__device__ __forceinline__ float sigmoidf_(float x){ return 1.0f/(1.0f+__expf(-x)); }

__device__ __forceinline__ unsigned short f2bf(float x){
  unsigned u = __float_as_uint(x);
  unsigned r = (u + 0x7FFFu + ((u>>16)&1u)) >> 16;
  return (unsigned short)r;
}
__device__ __forceinline__ float bf2f(unsigned short b){
  return __uint_as_float(((unsigned)b)<<16);
}
__device__ __forceinline__ short8 cvt8(const float* xv){
  union { short8 v; unsigned short u[8]; } H;
  #pragma unroll
  for (int j=0;j<8;j++) H.u[j] = f2bf(xv[j]);
  return H.v;
}

__device__ __forceinline__ void gload_lds16(const void* gsrc, void* ldst){
  __builtin_amdgcn_global_load_lds(
    (const __attribute__((address_space(1))) void*)gsrc,
    (__attribute__((address_space(3))) void*)ldst, 16, 0, 0);
}

// ---------------- LN(s)*gamma -> bf16 ----------------
__global__ __launch_bounds__(64) void ln_s_kernel(const float* __restrict__ s,
                                                  const float* __restrict__ gamma,
                                                  unsigned short* __restrict__ oh){
  int row = blockIdx.x, lane = threadIdx.x;
  const float* x = s + (size_t)row*CS;
  float v[6]; float sum=0.f, sq=0.f;
  #pragma unroll
  for (int i=0;i<6;i++){ v[i]=x[lane+64*i]; sum+=v[i]; sq+=v[i]*v[i]; }
  #pragma unroll
  for (int off=32; off; off>>=1){ sum+=__shfl_xor(sum,off); sq+=__shfl_xor(sq,off); }
  float m = sum*(1.f/CS);
  float var = sq*(1.f/CS)-m*m;
  float rs = rsqrtf(var+1e-5f);
  #pragma unroll
  for (int i=0;i<6;i++){
    int c = lane+64*i;
    oh[(size_t)row*CS+c] = f2bf((v[i]-m)*rs*gamma[c]);
  }
}

// ---------------- LN(a) -> fp32 ----------------
__global__ __launch_bounds__(64) void ln_a_kernel(const float* __restrict__ a,
                                                  float* __restrict__ out){
  int row = blockIdx.x, lane = threadIdx.x;
  const float* x = a + (size_t)row*CA;
  float v[12]; float sum=0.f, sq=0.f;
  #pragma unroll
  for (int i=0;i<12;i++){ v[i]=x[lane+64*i]; sum+=v[i]; sq+=v[i]*v[i]; }
  #pragma unroll
  for (int off=32; off; off>>=1){ sum+=__shfl_xor(sum,off); sq+=__shfl_xor(sq,off); }
  float m = sum*(1.f/CA);
  float var = sq*(1.f/CA)-m*m;
  float rs = rsqrtf(var+1e-5f);
  float* o = out + (size_t)row*CA;
  #pragma unroll
  for (int i=0;i<12;i++) o[lane+64*i] = (v[i]-m)*rs;
}

// ---------------- fp32 -> bf16 ----------------
__global__ __launch_bounds__(256) void cvt_kernel(const float* __restrict__ src,
                                                  unsigned short* __restrict__ dh, int n){
  int i = blockIdx.x*256 + threadIdx.x;
  if (i < n) dh[i] = f2bf(src[i]);
}

// ---------------- transpose + cvt weights: src[K][N] -> dst[N][K] bf16 ----------------
__global__ __launch_bounds__(256) void cvtT_kernel(const float* __restrict__ src,
                                                   unsigned short* __restrict__ dh,
                                                   int K, int N){
  __shared__ float tile[64][65];
  int kb = blockIdx.x*64, nb = blockIdx.y*64;
  int tid = threadIdx.x;
  int c = tid & 63, r0 = tid >> 6;
  #pragma unroll
  for (int i=0;i<16;i++){
    int r = r0 + 4*i;
    tile[r][c] = src[(size_t)(kb+r)*N + nb + c];
  }
  __syncthreads();
  #pragma unroll
  for (int i=0;i<16;i++){
    int r = r0 + 4*i;          // n-local
    dh[(size_t)(nb+r)*K + kb + c] = f2bf(tile[c][r]);
  }
}

// ---------------- zbias (MFMA, single bf16): bias3[wq][h][k] = LN(z_row)*gamma @ wz ----------------
__global__ __launch_bounds__(256) void zbias_kernel(const float* __restrict__ z,
                                                    const float* __restrict__ gamma,
                                                    const float* __restrict__ wz,
                                                    float* __restrict__ bias3){
  __shared__ float tbuf[4][16*132];
  int tid = threadIdx.x, wave = tid>>6, lane = tid&63;
  int lr = lane&15, quad = lane>>4;

  short8 bwh[4];
  float w1 = 0.f;
  #pragma unroll
  for (int ks=0;ks<4;ks++){
    float wv[8];
    #pragma unroll
    for (int j=0;j<8;j++){
      int k = ks*32 + quad*8 + j;
      wv[j] = wz[k*NHEAD + lr]*gamma[k];
      w1 += wv[j];
    }
    bwh[ks] = cvt8(wv);
  }
  w1 += __shfl_xor(w1, 16);
  w1 += __shfl_xor(w1, 32);

  size_t group = (size_t)blockIdx.x*4 + wave;   // = w*32+q, 0..4095
  const float* zg = z + group*(size_t)(NKW*CZ);

  #pragma unroll 1
  for (int b=0;b<8;b++){
    int row = b*16 + lr;
    const float* zr = zg + (size_t)row*CZ;
    float x[4][8];
    float sum=0.f, sq=0.f;
    #pragma unroll
    for (int ks=0;ks<4;ks++){
      float4 p0 = *(const float4*)(zr + ks*32 + quad*8);
      float4 p1 = *(const float4*)(zr + ks*32 + quad*8 + 4);
      x[ks][0]=p0.x; x[ks][1]=p0.y; x[ks][2]=p0.z; x[ks][3]=p0.w;
      x[ks][4]=p1.x; x[ks][5]=p1.y; x[ks][6]=p1.z; x[ks][7]=p1.w;
      #pragma unroll
      for (int j=0;j<8;j++){ sum += x[ks][j]; sq += x[ks][j]*x[ks][j]; }
    }
    sum += __shfl_xor(sum,16); sum += __shfl_xor(sum,32);
    sq  += __shfl_xor(sq,16);  sq  += __shfl_xor(sq,32);
    float mean = sum*(1.f/CZ);
    float var = sq*(1.f/CZ) - mean*mean;
    float rs = rsqrtf(var + 1e-5f);

    float4v c = (float4v){0.f,0.f,0.f,0.f};
    #pragma unroll
    for (int ks=0;ks<4;ks++){
      c = __builtin_amdgcn_mfma_f32_16x16x32_bf16(cvt8(x[ks]), bwh[ks], c, 0,0,0);
    }
    #pragma unroll
    for (int r=0;r<4;r++){
      int rrow = quad*4 + r;
      float m_r  = __shfl(mean, rrow);
      float rs_r = __shfl(rs, rrow);
      tbuf[wave][lr*132 + b*16 + rrow] = rs_r*(c[r] - m_r*w1);
    }
  }
  #pragma unroll
  for (int i=0;i<8;i++){
    int h = i*2 + (lane>>5);
    int koff = (lane&31)*4;
    float4 vv = *(const float4*)&tbuf[wave][h*132 + koff];
    *(float4*)(bias3 + group*2048 + h*128 + koff) = vv;
  }
}

// ---------------- single-bf16 MFMA GEMM, m97 structure ----------------
// C[m][n] = sum_k A[m][k]*Wt[n][k]
// MODE 0: out = acc1 + bias1
// MODE 2: out = sigmoid(acc1 + bias1) * aux
// MODE 3: out = sigmoid(acc2 + bias2) * (acc1 + bias1)   (second K-loop over A2/B2)
template<int MODE>
__global__ __launch_bounds__(256) void gemm_bf16(
  const unsigned short* __restrict__ A1, const unsigned short* __restrict__ B1,
  const float* __restrict__ bias1, int K1,
  const unsigned short* __restrict__ A2, const unsigned short* __restrict__ B2,
  const float* __restrict__ bias2, int K2,
  const float* __restrict__ aux, float* __restrict__ out, int M, int N)
{
  __shared__ unsigned short Ash[128*32];
  __shared__ unsigned short Bsh[128*32];

  int tid = threadIdx.x;
  int w = tid >> 6, lane = tid & 63;
  int lr = lane & 15, quad = lane >> 4;
  int m0 = blockIdx.y*128, n0 = blockIdx.x*128;
  int mbase = (w&1)*64, nbase = (w>>1)*64;

  float4v acc1[4][4];
  float4v acc2[4][4];
  #pragma unroll
  for (int i=0;i<4;i++)
    #pragma unroll
    for (int j=0;j<4;j++){
      acc1[i][j] = (float4v){0.f,0.f,0.f,0.f};
      acc2[i][j] = (float4v){0.f,0.f,0.f,0.f};
    }

  int grow = w*32 + (lane>>2);
  int gcol8 = (lane&3)*8;

  for (int k0=0; k0<K1; k0+=32){
    __syncthreads();
    #pragma unroll
    for (int i=0;i<2;i++){
      int rA = grow + i*16;
      gload_lds16(A1 + (size_t)(m0 + rA)*K1 + k0 + gcol8, &Ash[(w*32 + i*16)*32]);
      gload_lds16(B1 + (size_t)(n0 + rA)*K1 + k0 + gcol8, &Bsh[(w*32 + i*16)*32]);
    }
    __syncthreads();

    short8 af[4], bf[4];
    #pragma unroll
    for (int mi=0;mi<4;mi++)
      af[mi] = *(const short8*)&Ash[(mbase + mi*16 + lr)*32 + quad*8];
    #pragma unroll
    for (int ni=0;ni<4;ni++)
      bf[ni] = *(const short8*)&Bsh[(nbase + ni*16 + lr)*32 + quad*8];
    #pragma unroll
    for (int mi=0;mi<4;mi++)
      #pragma unroll
      for (int ni=0;ni<4;ni++)
        acc1[mi][ni] = __builtin_amdgcn_mfma_f32_16x16x32_bf16(af[mi], bf[ni], acc1[mi][ni], 0,0,0);
  }

  if constexpr (MODE == 3){
    for (int k0=0; k0<K2; k0+=32){
      __syncthreads();
      #pragma unroll
      for (int i=0;i<2;i++){
        int rA = grow + i*16;
        gload_lds16(A2 + (size_t)(m0 + rA)*K2 + k0 + gcol8, &Ash[(w*32 + i*16)*32]);
        gload_lds16(B2 + (size_t)(n0 + rA)*K2 + k0 + gcol8, &Bsh[(w*32 + i*16)*32]);
      }
      __syncthreads();

      short8 af[4], bf[4];
      #pragma unroll
      for (int mi=0;mi<4;mi++)
        af[mi] = *(const short8*)&Ash[(mbase + mi*16 + lr)*32 + quad*8];
      #pragma unroll
      for (int ni=0;ni<4;ni++)
        bf[ni] = *(const short8*)&Bsh[(nbase + ni*16 + lr)*32 + quad*8];
      #pragma unroll
      for (int mi=0;mi<4;mi++)
        #pragma unroll
        for (int ni=0;ni<4;ni++)
          acc2[mi][ni] = __builtin_amdgcn_mfma_f32_16x16x32_bf16(af[mi], bf[ni], acc2[mi][ni], 0,0,0);
    }
  }

  #pragma unroll
  for (int ni=0;ni<4;ni++){
    int col = n0 + nbase + ni*16 + lr;
    float bv1 = bias1 ? bias1[col] : 0.f;
    float bv2 = (MODE==3 && bias2) ? bias2[col] : 0.f;
    #pragma unroll
    for (int mi=0;mi<4;mi++){
      #pragma unroll
      for (int reg=0;reg<4;reg++){
        int row = m0 + mbase + mi*16 + quad*4 + reg;
        float x1 = acc1[mi][ni][reg] + bv1;
        float v;
        if constexpr (MODE == 0)      v = x1;
        else if constexpr (MODE == 2) v = sigmoidf_(x1)*aux[(size_t)row*N + col];
        else                          v = sigmoidf_(acc2[mi][ni][reg] + bv2)*x1;
        out[(size_t)row*N + col] = v;
      }
    }
  }
}

// ---------------- adaln combine: a_ln = sigmoid(t1+bs)*a_n + t2 -> bf16 ----------------
__global__ __launch_bounds__(256) void adaln_combine(const float* __restrict__ t12,
                                                     const float* __restrict__ a_n,
                                                     const float* __restrict__ bs,
                                                     unsigned short* __restrict__ ah){
  int idx = blockIdx.x*256 + threadIdx.x;
  int r = idx / 192, cq = (idx - r*192)*4;
  float4 t1 = *(const float4*)(t12 + (size_t)r*1536 + cq);
  float4 t2 = *(const float4*)(t12 + (size_t)r*1536 + 768 + cq);
  float4 an = *(const float4*)(a_n + (size_t)r*768 + cq);
  float4 b  = *(const float4*)(bs + cq);
  float v[4] = { sigmoidf_(t1.x+b.x)*an.x + t2.x,
                 sigmoidf_(t1.y+b.y)*an.y + t2.y,
                 sigmoidf_(t1.z+b.z)*an.z + t2.z,
                 sigmoidf_(t1.w+b.w)*an.w + t2.w };
  #pragma unroll
  for (int j=0;j<4;j++) ah[(size_t)r*768 + cq + j] = f2bf(v[j]);
}

// ---------------- attention: one wave per (w,h), single-bf16 MFMA, register softmax ----------------
__global__ __launch_bounds__(256) void attn_kernel(
  const float* __restrict__ qkvg, const float* __restrict__ bq, const float* __restrict__ bg,
  const float* __restrict__ bias3, unsigned short* __restrict__ og)
{
  __shared__ unsigned short Pb[4][32*72];
  int tid = threadIdx.x, wave = tid>>6, lane = tid&63;
  int lr = lane&15, quad = lane>>4;
  int w = blockIdx.x, h = blockIdx.y*4 + wave;
  int start = w*NQW - 48;
  const float scale = 0.14433756729740643f;  // 1/sqrt(48)

  // Q A-frags: m=lr -> q row; k = ks*32 + quad*8 + j (d, pad 48->64)
  short8 aq[2][2];
  #pragma unroll
  for (int mt=0;mt<2;mt++){
    int row = w*NQW + mt*16 + lr;
    #pragma unroll
    for (int ks=0;ks<2;ks++){
      float xv[8];
      if (ks==1 && quad>=2){
        #pragma unroll
        for (int j=0;j<8;j++) xv[j]=0.f;
      } else {
        const float* qp = qkvg + (size_t)row*3072 + h*DH + ks*32 + quad*8;
        const float* bp = bq + h*DH + ks*32 + quad*8;
        float4 a0 = *(const float4*)qp, a1 = *(const float4*)(qp+4);
        float4 b0 = *(const float4*)bp, b1 = *(const float4*)(bp+4);
        xv[0]=a0.x+b0.x; xv[1]=a0.y+b0.y; xv[2]=a0.z+b0.z; xv[3]=a0.w+b0.w;
        xv[4]=a1.x+b1.x; xv[5]=a1.y+b1.y; xv[6]=a1.z+b1.z; xv[7]=a1.w+b1.w;
      }
      aq[mt][ks] = cvt8(xv);
    }
  }

  // QK^T
  float4v c[2][8];
  #pragma unroll
  for (int mt=0;mt<2;mt++)
    #pragma unroll
    for (int nt=0;nt<8;nt++) c[mt][nt] = (float4v){0.f,0.f,0.f,0.f};

  #pragma unroll 1
  for (int nt=0;nt<8;nt++){
    int krow = start + nt*16 + lr;
    int krc = min(max(krow,0),N_TOK-1);
    short8 bk[2];
    #pragma unroll
    for (int ks=0;ks<2;ks++){
      float xv[8];
      if (ks==1 && quad>=2){
        #pragma unroll
        for (int j=0;j<8;j++) xv[j]=0.f;
      } else {
        const float* kp = qkvg + (size_t)krc*3072 + 768 + h*DH + ks*32 + quad*8;
        float4 a0 = *(const float4*)kp, a1 = *(const float4*)(kp+4);
        xv[0]=a0.x; xv[1]=a0.y; xv[2]=a0.z; xv[3]=a0.w;
        xv[4]=a1.x; xv[5]=a1.y; xv[6]=a1.z; xv[7]=a1.w;
      }
      bk[ks] = cvt8(xv);
    }
    #pragma unroll
    for (int mt=0;mt<2;mt++)
      #pragma unroll
      for (int ks=0;ks<2;ks++)
        c[mt][nt] = __builtin_amdgcn_mfma_f32_16x16x32_bf16(aq[mt][ks], bk[ks], c[mt][nt], 0,0,0);
  }

  // bias + mask + softmax in registers (C: col=key=nt*16+lr, row=quad*4+reg)
  float rmax[2][4], rsum[2][4];
  #pragma unroll
  for (int mt=0;mt<2;mt++)
    #pragma unroll
    for (int r=0;r<4;r++){ rmax[mt][r] = -3.0e38f; rsum[mt][r] = 0.f; }

  #pragma unroll
  for (int nt=0;nt<8;nt++){
    int key = start + nt*16 + lr;
    bool valid = (key>=0) && (key<N_TOK);
    #pragma unroll
    for (int mt=0;mt<2;mt++){
      #pragma unroll
      for (int r=0;r<4;r++){
        int q = mt*16 + quad*4 + r;
        float bv = bias3[(((size_t)(w*NQW+q))*NHEAD + h)*128 + nt*16 + lr];
        float v = valid ? (c[mt][nt][r]*scale + bv) : -1e9f;
        c[mt][nt][r] = v;
        rmax[mt][r] = fmaxf(rmax[mt][r], v);
      }
    }
  }
  #pragma unroll
  for (int mt=0;mt<2;mt++)
    #pragma unroll
    for (int r=0;r<4;r++){
      float m = rmax[mt][r];
      m = fmaxf(m, __shfl_xor(m,1)); m = fmaxf(m, __shfl_xor(m,2));
      m = fmaxf(m, __shfl_xor(m,4)); m = fmaxf(m, __shfl_xor(m,8));
      rmax[mt][r] = m;
    }
  #pragma unroll
  for (int nt=0;nt<8;nt++)
    #pragma unroll
    for (int mt=0;mt<2;mt++)
      #pragma unroll
      for (int r=0;r<4;r++){
        float e = __expf(c[mt][nt][r] - rmax[mt][r]);
        c[mt][nt][r] = e;
        rsum[mt][r] += e;
      }
  #pragma unroll
  for (int mt=0;mt<2;mt++)
    #pragma unroll
    for (int r=0;r<4;r++){
      float sv = rsum[mt][r];
      sv += __shfl_xor(sv,1); sv += __shfl_xor(sv,2);
      sv += __shfl_xor(sv,4); sv += __shfl_xor(sv,8);
      rsum[mt][r] = 1.f/sv;
    }

  // PV: P through LDS (A-layout), V B-frags from global
  unsigned short* ph = &Pb[wave][0];
  float4v o[2][3];
  #pragma unroll
  for (int mt=0;mt<2;mt++)
    #pragma unroll
    for (int no=0;no<3;no++) o[mt][no] = (float4v){0.f,0.f,0.f,0.f};

  #pragma unroll 1
  for (int c2=0;c2<2;c2++){
    #pragma unroll
    for (int nt4=0;nt4<4;nt4++){
      int nt = c2*4 + nt4;
      #pragma unroll
      for (int mt=0;mt<2;mt++){
        #pragma unroll
        for (int r=0;r<4;r++){
          int q = mt*16 + quad*4 + r;
          ph[q*72 + nt4*16 + lr] = f2bf(c[mt][nt][r]*rsum[mt][r]);
        }
      }
    }
    #pragma unroll 1
    for (int ks=0;ks<2;ks++){
      short8 pa[2];
      #pragma unroll
      for (int mt=0;mt<2;mt++)
        pa[mt] = *(const short8*)&ph[(mt*16+lr)*72 + ks*32 + quad*8];
      #pragma unroll
      for (int no=0;no<3;no++){
        int d = no*16 + lr;
        float xv[8];
        #pragma unroll
        for (int j=0;j<8;j++){
          int key = c2*64 + ks*32 + quad*8 + j;
          int kr = min(max(start+key,0),N_TOK-1);
          xv[j] = qkvg[(size_t)kr*3072 + 1536 + h*DH + d];
        }
        short8 bv = cvt8(xv);
        #pragma unroll
        for (int mt=0;mt<2;mt++)
          o[mt][no] = __builtin_amdgcn_mfma_f32_16x16x32_bf16(pa[mt], bv, o[mt][no], 0,0,0);
      }
    }
  }

  // epilogue: gate + store bf16
  #pragma unroll
  for (int mt=0;mt<2;mt++){
    #pragma unroll
    for (int no=0;no<3;no++){
      int d = no*16 + lr;
      #pragma unroll
      for (int r=0;r<4;r++){
        int q = mt*16 + quad*4 + r;
        size_t grow = (size_t)(w*NQW + q);
        float g = qkvg[grow*3072 + 2304 + h*DH + d] + bg[h*DH + d];
        og[grow*CA + h*DH + d] = f2bf(o[mt][no][r] * sigmoidf_(g));
      }
    }
  }
}

extern "C" void kernel_launch(void* const* d_in, const int* in_sizes, int n_in,
                              void* d_out, int out_size, void* d_ws, size_t ws_size,
                              hipStream_t stream)
{
  const float* a            = (const float*)d_in[0];
  const float* s            = (const float*)d_in[1];
  const float* z            = (const float*)d_in[2];
  const float* adaln_gamma  = (const float*)d_in[3];
  const float* adaln_ws     = (const float*)d_in[4];
  const float* adaln_bs     = (const float*)d_in[5];
  const float* adaln_wskip  = (const float*)d_in[6];
  const float* lnz_gamma    = (const float*)d_in[7];
  const float* wz           = (const float*)d_in[8];
  const float* wq           = (const float*)d_in[9];
  const float* bq           = (const float*)d_in[10];
  const float* wk           = (const float*)d_in[11];
  const float* wv           = (const float*)d_in[12];
  const float* wg           = (const float*)d_in[13];
  const float* bg           = (const float*)d_in[14];
  const float* wo           = (const float*)d_in[15];
  const float* bo           = (const float*)d_in[16];
  const float* w_last       = (const float*)d_in[17];
  const float* b_last       = (const float*)d_in[18];
  float* out = (float*)d_out;

  char* base = (char*)d_ws;
  size_t off = 0;
  auto alloc = [&](size_t bytes)->char*{ char* p = base + off; off += (bytes + 255) & ~(size_t)255; return p; };

  unsigned short* s_ln_h = (unsigned short*)alloc((size_t)N_TOK*CS*2);
  unsigned short* s_h    = (unsigned short*)alloc((size_t)N_TOK*CS*2);
  float*          a_n    = (float*)alloc((size_t)N_TOK*CA*4);
  unsigned short* a_ln_h = (unsigned short*)alloc((size_t)N_TOK*CA*2);
  unsigned short* og_h   = (unsigned short*)alloc((size_t)N_TOK*CA*2);
  unsigned short* Wt1    = (unsigned short*)alloc((size_t)1536*CS*2);
  unsigned short* Wt2    = (unsigned short*)alloc((size_t)3072*CA*2);
  unsigned short* Wt3    = (unsigned short*)alloc((size_t)CA*CA*2);
  unsigned short* Wt4    = (unsigned short*)alloc((size_t)CA*CS*2);
  float*          bias3  = (float*)alloc((size_t)N_TOK*NHEAD*NKW*4);   // [wq][h][k]
  float*          big    = (float*)alloc((size_t)N_TOK*3072*4);
  float* t12  = big;   // [4096][1536]
  float* qkvg = big;   // [4096][3072]

  ln_s_kernel<<<dim3(N_TOK), dim3(64), 0, stream>>>(s, adaln_gamma, s_ln_h);
  ln_a_kernel<<<dim3(N_TOK), dim3(64), 0, stream>>>(a, a_n);
  cvt_kernel<<<dim3((N_TOK*CS)/256), 256, 0, stream>>>(s, s_h, N_TOK*CS);

  cvtT_kernel<<<dim3(CS/64, CA/64), 256, 0, stream>>>(adaln_ws,    Wt1,           CS, CA);
  cvtT_kernel<<<dim3(CS/64, CA/64), 256, 0, stream>>>(adaln_wskip, Wt1 + 768*CS,  CS, CA);
  cvtT_kernel<<<dim3(CA/64, CA/64), 256, 0, stream>>>(wq,          Wt2,           CA, CA);
  cvtT_kernel<<<dim3(CA/64, CA/64), 256, 0, stream>>>(wk,          Wt2 + 768*CA,  CA, CA);
  cvtT_kernel<<<dim3(CA/64, CA/64), 256, 0, stream>>>(wv,          Wt2 + 1536*CA, CA, CA);
  cvtT_kernel<<<dim3(CA/64, CA/64), 256, 0, stream>>>(wg,          Wt2 + 2304*CA, CA, CA);
  cvtT_kernel<<<dim3(CA/64, CA/64), 256, 0, stream>>>(wo,          Wt3,           CA, CA);
  cvtT_kernel<<<dim3(CS/64, CA/64), 256, 0, stream>>>(w_last,      Wt4,           CS, CA);

  zbias_kernel<<<dim3(N_TOK/4), 256, 0, stream>>>(z, lnz_gamma, wz, bias3);

  // t12 = s_ln @ [ws|wskip]
  gemm_bf16<0><<<dim3(1536/128, N_TOK/128), 256, 0, stream>>>(
      s_ln_h, Wt1, nullptr, CS, nullptr, nullptr, nullptr, 0, nullptr, t12, N_TOK, 1536);
  adaln_combine<<<dim3((N_TOK*192)/256), 256, 0, stream>>>(t12, a_n, adaln_bs, a_ln_h);

  // qkvg = a_ln @ [wq|wk|wv|wg]
  gemm_bf16<0><<<dim3(3072/128, N_TOK/128), 256, 0, stream>>>(
      a_ln_h, Wt2, nullptr, CA, nullptr, nullptr, nullptr, 0, nullptr, qkvg, N_TOK, 3072);

  attn_kernel<<<dim3(NBLK, 4), 256, 0, stream>>>(qkvg, bq, bg, bias3, og_h);

  // out = sigmoid(s@w_last + b_last) * (og@wo + bo)   (fused dual-K GEMM)
  gemm_bf16<3><<<dim3(CA/128, N_TOK/128), 256, 0, stream>>>(
      og_h, Wt3, bo, CA, s_h, Wt4, b_last, CS, nullptr, out, N_TOK, CA);
}